// Round 2
// baseline (617.776 us; speedup 1.0000x reference)
//
#include <hip/hip_runtime.h>
#include <hip/hip_bf16.h>
#include <cstdint>
#include <cfloat>

#define BATCH   4096
#define IN_DIM  1024
#define D_MODEL 1024
#define BRANCH  16
#define HEIGHT  4
#define N_NODES 69904   // 16 + 256 + 4096 + 65536

// ---------------------------------------------------------------------------
// fp32 GEMM: C[M,N] = A[M,K]*B[K,N]. BM=128, BN=64, BK=16, 128 thr, 8x8/thread.
// 64 FMA per 4 ds_read_b128 per k-step = 2 flop/LDS-byte -> LDS no longer the
// cap (was 1 flop/byte at 4x4). Register-double-buffered global staging.
// ---------------------------------------------------------------------------
#define BM 128
#define BN 64
#define BK 16

__global__ __launch_bounds__(128) void gemm_f32(const float* __restrict__ A,
                                                const float* __restrict__ B,
                                                float* __restrict__ C) {
    __shared__ float As[BK][BM + 4];   // [k][m]
    __shared__ float Bs[BK][BN + 4];   // [k][n]

    const int t  = threadIdx.x;
    const int tx = t & 7;          // 8 col-groups
    const int ty = t >> 3;         // 16 row-groups
    const int bm = blockIdx.x;
    const int bn = blockIdx.y;

    const int arow = t >> 2;             // 0..31
    const int ac4  = (t & 3) * 4;
    const float* Ab = A + (size_t)bm * BM * IN_DIM;
    const float* Bb = B + (size_t)bn * BN;

    float4 ar[4], br[2];

#define LOAD_TILE(k0)                                                          \
    {                                                                          \
        _Pragma("unroll")                                                      \
        for (int i = 0; i < 4; ++i)                                            \
            ar[i] = *(const float4*)(Ab + (size_t)(arow + 32 * i) * IN_DIM +   \
                                     (k0) + ac4);                              \
        _Pragma("unroll")                                                      \
        for (int i = 0; i < 2; ++i) {                                          \
            int idx = t + 128 * i;                                             \
            br[i] = *(const float4*)(Bb + (size_t)((k0) + (idx >> 4)) * D_MODEL\
                                     + (idx & 15) * 4);                        \
        }                                                                      \
    }

#define STORE_TILE()                                                           \
    {                                                                          \
        _Pragma("unroll")                                                      \
        for (int i = 0; i < 4; ++i) {                                          \
            As[ac4 + 0][arow + 32 * i] = ar[i].x;                              \
            As[ac4 + 1][arow + 32 * i] = ar[i].y;                              \
            As[ac4 + 2][arow + 32 * i] = ar[i].z;                              \
            As[ac4 + 3][arow + 32 * i] = ar[i].w;                              \
        }                                                                      \
        _Pragma("unroll")                                                      \
        for (int i = 0; i < 2; ++i) {                                          \
            int idx = t + 128 * i;                                             \
            *(float4*)&Bs[idx >> 4][(idx & 15) * 4] = br[i];                   \
        }                                                                      \
    }

    float acc[8][8] = {};

#define COMPUTE_TILE()                                                         \
    {                                                                          \
        _Pragma("unroll")                                                      \
        for (int k = 0; k < BK; ++k) {                                         \
            float4 a0 = *(const float4*)&As[k][ty * 8];                        \
            float4 a1 = *(const float4*)&As[k][ty * 8 + 4];                    \
            float4 b0 = *(const float4*)&Bs[k][tx * 8];                        \
            float4 b1 = *(const float4*)&Bs[k][tx * 8 + 4];                    \
            const float aa[8] = {a0.x, a0.y, a0.z, a0.w, a1.x, a1.y, a1.z, a1.w};\
            const float bb[8] = {b0.x, b0.y, b0.z, b0.w, b1.x, b1.y, b1.z, b1.w};\
            _Pragma("unroll")                                                  \
            for (int i = 0; i < 8; ++i)                                        \
                _Pragma("unroll")                                              \
                for (int j = 0; j < 8; ++j)                                    \
                    acc[i][j] = fmaf(aa[i], bb[j], acc[i][j]);                 \
        }                                                                      \
    }

    LOAD_TILE(0);
    STORE_TILE();
    __syncthreads();

    for (int k0 = BK; k0 < IN_DIM; k0 += BK) {
        LOAD_TILE(k0);       // issue next-tile loads; compute hides latency
        COMPUTE_TILE();
        __syncthreads();
        STORE_TILE();
        __syncthreads();
    }
    COMPUTE_TILE();

    float* Cb = C + (size_t)(bm * BM + ty * 8) * D_MODEL + bn * BN + tx * 8;
#pragma unroll
    for (int i = 0; i < 8; ++i) {
        float4 v0 = {acc[i][0], acc[i][1], acc[i][2], acc[i][3]};
        float4 v1 = {acc[i][4], acc[i][5], acc[i][6], acc[i][7]};
        *(float4*)(Cb + (size_t)i * D_MODEL)     = v0;
        *(float4*)(Cb + (size_t)i * D_MODEL + 4) = v1;
    }
#undef LOAD_TILE
#undef STORE_TILE
#undef COMPUTE_TILE
}

// ---------------------------------------------------------------------------
// Tree descent, one wave per batch row. lane = (dg, q): dg = lane>>2 is the
// d-phase (16 of them), q = lane&3 is the candidate quad. The 16 children of
// a node are CONTIGUOUS columns of Xi, 16-aligned, so each lane float4-loads
// 4 candidates at one d-row: the wave moves 1KB/instr, 64 instrs/level
// (was 256 scalar-load iters). Children row is wave-uniform -> readfirstlane.
// Complete 16-ary tree of height 4 => every visited node has valid children.
// ---------------------------------------------------------------------------
__global__ __launch_bounds__(256) void descend(const float* __restrict__ f,
                                               const float* __restrict__ Xi,
                                               const int* __restrict__ children,
                                               int* __restrict__ out) {
    __shared__ float fs[4][1024];

    const int lane = threadIdx.x & 63;
    const int w    = threadIdx.x >> 6;
    const int b    = blockIdx.x * 4 + w;

    {
        const float4* frow = (const float4*)(f + (size_t)b * D_MODEL);
        float4* fsw = (float4*)fs[w];
#pragma unroll
        for (int i = 0; i < 4; ++i) fsw[lane + 64 * i] = frow[lane + 64 * i];
    }
    __syncthreads();

    const int q  = lane & 3;    // candidate quad: candidates 4q..4q+3
    const int dg = lane >> 2;   // d-group 0..15: d = dg + 16*t
    const float* frd = fs[w] + dg;

    int cur = 0;
    if (lane == 0) out[(size_t)b * (HEIGHT + 1)] = 0;

    for (int lev = 0; lev < HEIGHT; ++lev) {
        const int child0 = __builtin_amdgcn_readfirstlane(children[cur * BRANCH]);
        // columns child0-1 .. child0+14 are this node's children; 16-aligned.
        const float* xp = Xi + (size_t)dg * N_NODES + (child0 - 1) + q * 4;

        float4 acc = {0.f, 0.f, 0.f, 0.f};
#pragma unroll 8
        for (int t = 0; t < 64; ++t) {
            float4 x = *(const float4*)xp;
            float fv = frd[16 * t];
            acc.x = fmaf(fv, x.x, acc.x);
            acc.y = fmaf(fv, x.y, acc.y);
            acc.z = fmaf(fv, x.z, acc.z);
            acc.w = fmaf(fv, x.w, acc.w);
            xp += (size_t)16 * N_NODES;
        }

        // sum over the 16 d-groups (lanes sharing q): xor 4,8,16,32
#pragma unroll
        for (int m = 4; m <= 32; m <<= 1) {
            acc.x += __shfl_xor(acc.x, m);
            acc.y += __shfl_xor(acc.y, m);
            acc.z += __shfl_xor(acc.z, m);
            acc.w += __shfl_xor(acc.w, m);
        }

        // local argmax over the 4 candidates in this lane (first-max wins)
        float bv = acc.x; int bc = q * 4;
        if (acc.y > bv) { bv = acc.y; bc = q * 4 + 1; }
        if (acc.z > bv) { bv = acc.z; bc = q * 4 + 2; }
        if (acc.w > bv) { bv = acc.w; bc = q * 4 + 3; }

        // combine across the 4 q-groups; tie -> smaller candidate index
#pragma unroll
        for (int m = 1; m <= 2; m <<= 1) {
            float ov = __shfl_xor(bv, m);
            int   oc = __shfl_xor(bc, m);
            if (ov > bv || (ov == bv && oc < bc)) { bv = ov; bc = oc; }
        }

        const int nxt = child0 + bc;   // node id of winning child
        if (lane == 0) out[(size_t)b * (HEIGHT + 1) + lev + 1] = nxt;
        cur = nxt;
    }
}

// ---------------------------------------------------------------------------
extern "C" void kernel_launch(void* const* d_in, const int* in_sizes, int n_in,
                              void* d_out, int out_size, void* d_ws, size_t ws_size,
                              hipStream_t stream) {
    const float* X        = (const float*)d_in[0];   // [BATCH, IN_DIM]
    const float* W        = (const float*)d_in[1];   // [IN_DIM, D_MODEL]
    const float* Xi       = (const float*)d_in[2];   // [D_MODEL, N_NODES]
    const int*   children = (const int*)d_in[3];     // [N_NODES+1, BRANCH]
    int* out = (int*)d_out;                          // [BATCH, HEIGHT+1] int32

    float* f = (float*)d_ws;                         // [BATCH, D_MODEL] scratch

    dim3 ggrid(BATCH / BM, D_MODEL / BN);
    gemm_f32<<<ggrid, 128, 0, stream>>>(X, W, f);

    descend<<<BATCH / 4, 256, 0, stream>>>(f, Xi, children, out);
}

// Round 3
// 613.662 us; speedup vs baseline: 1.0067x; 1.0067x over previous
//
#include <hip/hip_runtime.h>
#include <hip/hip_bf16.h>
#include <cstdint>
#include <cfloat>

#define BATCH   4096
#define IN_DIM  1024
#define D_MODEL 1024
#define BRANCH  16
#define HEIGHT  4
#define N_NODES 69904   // 16 + 256 + 4096 + 65536

// ---------------------------------------------------------------------------
// fp32 GEMM: C = A[4096,1024] * B[1024,1024]. BM=BN=128, BK=16, 256 thr,
// 8x8/thread -> 2 flop/LDS-byte (VALU-balanced). Grid 256 = 1 block/CU.
// B-fragment is cols {tx*4, tx*4+64}: Bs reads become 2-way (free) instead
// of 4-way (1.58x). A-reads are 16-lane broadcasts (conflict-free).
// Register double-buffer: next tile's global loads issue before compute.
// ---------------------------------------------------------------------------
#define BM 128
#define BN 128
#define BK 16

__global__ __launch_bounds__(256) void gemm_f32(const float* __restrict__ A,
                                                const float* __restrict__ B,
                                                float* __restrict__ C) {
    __shared__ float As[BK][BM + 4];   // [k][m]
    __shared__ float Bs[BK][BN + 4];   // [k][n]

    const int t  = threadIdx.x;
    const int tx = t & 15;         // 16 col-groups
    const int ty = t >> 4;         // 16 row-groups
    const int bm = blockIdx.x;
    const int bn = blockIdx.y;

    const int arow = t >> 2;             // 0..63
    const int ac4  = (t & 3) * 4;        // 0,4,8,12
    const int brow = t >> 5;             // 0..7
    const int bc4  = (t & 31) * 4;       // 0..124

    const float* Ab = A + (size_t)bm * BM * IN_DIM;
    const float* Bb = B + (size_t)bn * BN;

    float4 ar[2], br[2];

#define LOAD_TILE(k0)                                                          \
    {                                                                          \
        _Pragma("unroll")                                                      \
        for (int i = 0; i < 2; ++i)                                            \
            ar[i] = *(const float4*)(Ab + (size_t)(arow + 64 * i) * IN_DIM +   \
                                     (k0) + ac4);                              \
        _Pragma("unroll")                                                      \
        for (int i = 0; i < 2; ++i)                                            \
            br[i] = *(const float4*)(Bb + (size_t)((k0) + brow + 8 * i) *      \
                                     D_MODEL + bc4);                           \
    }

#define STORE_TILE()                                                           \
    {                                                                          \
        _Pragma("unroll")                                                      \
        for (int i = 0; i < 2; ++i) {                                          \
            As[ac4 + 0][arow + 64 * i] = ar[i].x;                              \
            As[ac4 + 1][arow + 64 * i] = ar[i].y;                              \
            As[ac4 + 2][arow + 64 * i] = ar[i].z;                              \
            As[ac4 + 3][arow + 64 * i] = ar[i].w;                              \
        }                                                                      \
        _Pragma("unroll")                                                      \
        for (int i = 0; i < 2; ++i)                                            \
            *(float4*)&Bs[brow + 8 * i][bc4] = br[i];                          \
    }

    float acc[8][8] = {};

#define COMPUTE_TILE()                                                         \
    {                                                                          \
        _Pragma("unroll")                                                      \
        for (int k = 0; k < BK; ++k) {                                         \
            float4 a0 = *(const float4*)&As[k][ty * 8];                        \
            float4 a1 = *(const float4*)&As[k][ty * 8 + 4];                    \
            float4 b0 = *(const float4*)&Bs[k][tx * 4];                        \
            float4 b1 = *(const float4*)&Bs[k][tx * 4 + 64];                   \
            const float aa[8] = {a0.x, a0.y, a0.z, a0.w, a1.x, a1.y, a1.z, a1.w};\
            const float bb[8] = {b0.x, b0.y, b0.z, b0.w, b1.x, b1.y, b1.z, b1.w};\
            _Pragma("unroll")                                                  \
            for (int i = 0; i < 8; ++i)                                        \
                _Pragma("unroll")                                              \
                for (int j = 0; j < 8; ++j)                                    \
                    acc[i][j] = fmaf(aa[i], bb[j], acc[i][j]);                 \
        }                                                                      \
    }

    LOAD_TILE(0);
    STORE_TILE();
    __syncthreads();

    for (int k0 = BK; k0 < IN_DIM; k0 += BK) {
        LOAD_TILE(k0);       // next tile in regs; compute hides the latency
        COMPUTE_TILE();
        __syncthreads();
        STORE_TILE();
        __syncthreads();
    }
    COMPUTE_TILE();

    // cols tx*4..tx*4+3 hold acc[.][0..3]; cols tx*4+64.. hold acc[.][4..7]
    float* Cb = C + (size_t)(bm * BM + ty * 8) * D_MODEL + bn * BN;
#pragma unroll
    for (int i = 0; i < 8; ++i) {
        float4 v0 = {acc[i][0], acc[i][1], acc[i][2], acc[i][3]};
        float4 v1 = {acc[i][4], acc[i][5], acc[i][6], acc[i][7]};
        *(float4*)(Cb + (size_t)i * D_MODEL + tx * 4)      = v0;
        *(float4*)(Cb + (size_t)i * D_MODEL + tx * 4 + 64) = v1;
    }
#undef LOAD_TILE
#undef STORE_TILE
#undef COMPUTE_TILE
}

// ---------------------------------------------------------------------------
// Tree descent. Block = 256 thr = 4 waves = 2 rows x 2 d-halves.
// Grid 2048 -> 8 blocks/CU -> up to 32 waves/CU (was ~10): 3x the
// outstanding-request pool for the 64B-granule scattered Xi reads.
// Wave lane = (dg = lane>>2, q = lane&3): one float4 covers candidates
// 4q..4q+3 at d-row (h*512 + 16*i + dg); 32 x 1KB load-instrs per level.
// d-halves combine through LDS; argmax is computed redundantly by all lanes
// (no divergent shuffles).
// ---------------------------------------------------------------------------
__global__ __launch_bounds__(256, 6) void descend(const float* __restrict__ f,
                                                  const float* __restrict__ Xi,
                                                  const int* __restrict__ children,
                                                  int* __restrict__ out) {
    __shared__ float  fs[2][1024];
    __shared__ float4 part[2][2][4];   // [row][half][q]

    const int t    = threadIdx.x;
    const int lane = t & 63;
    const int w    = t >> 6;       // wave 0..3
    const int r    = w >> 1;       // row within block
    const int h    = w & 1;        // d-half
    const int b    = blockIdx.x * 2 + r;

    // stage both f rows (512 float4 by 256 threads)
    {
        const float4* src = (const float4*)(f + (size_t)blockIdx.x * 2 * D_MODEL);
        float4* dst = (float4*)fs;
        dst[t]       = src[t];
        dst[t + 256] = src[t + 256];
    }

    const int q  = lane & 3;
    const int dg = lane >> 2;
    const float*  frd   = fs[r] + h * 512 + dg;
    const size_t  dbase = (size_t)(h * 512 + dg) * N_NODES;

    if (w == 0 && lane == 0) out[(size_t)b * (HEIGHT + 1)] = 0;
    if (w == 2 && lane == 0) out[(size_t)(b) * (HEIGHT + 1)] = 0; // r=1 row

    __syncthreads();

    int cur = 0;
    for (int lev = 0; lev < HEIGHT; ++lev) {
        const int child0 = __builtin_amdgcn_readfirstlane(
            children[(size_t)cur * BRANCH]);
        const float* xp = Xi + dbase + (size_t)(child0 - 1) + q * 4;

        float4 acc = {0.f, 0.f, 0.f, 0.f};
#pragma unroll 8
        for (int i = 0; i < 32; ++i) {
            float4 x  = *(const float4*)xp;
            float  fv = frd[16 * i];
            acc.x = fmaf(fv, x.x, acc.x);
            acc.y = fmaf(fv, x.y, acc.y);
            acc.z = fmaf(fv, x.z, acc.z);
            acc.w = fmaf(fv, x.w, acc.w);
            xp += (size_t)16 * N_NODES;
        }

        // sum the 16 d-groups (lanes sharing q)
#pragma unroll
        for (int m = 4; m <= 32; m <<= 1) {
            acc.x += __shfl_xor(acc.x, m);
            acc.y += __shfl_xor(acc.y, m);
            acc.z += __shfl_xor(acc.z, m);
            acc.w += __shfl_xor(acc.w, m);
        }
        if (lane < 4) part[r][h][lane] = acc;
        __syncthreads();

        // every lane: combine the two d-halves, argmax over 16 candidates
        const float4 s0 = part[r][0][q];
        const float4 s1 = part[r][1][q];
        const float sv[4] = {s0.x + s1.x, s0.y + s1.y, s0.z + s1.z, s0.w + s1.w};
        float bv = sv[0];
        int   bc = q * 4;
#pragma unroll
        for (int j = 1; j < 4; ++j)
            if (sv[j] > bv) { bv = sv[j]; bc = q * 4 + j; }   // first-max wins
#pragma unroll
        for (int m = 1; m <= 2; m <<= 1) {
            float ov = __shfl_xor(bv, m);
            int   oc = __shfl_xor(bc, m);
            if (ov > bv || (ov == bv && oc < bc)) { bv = ov; bc = oc; }
        }

        cur = child0 + bc;                       // uniform across the row's waves
        if (h == 0 && lane == 0)
            out[(size_t)b * (HEIGHT + 1) + lev + 1] = cur;
        __syncthreads();                         // part[] reused next level
    }
}

// ---------------------------------------------------------------------------
extern "C" void kernel_launch(void* const* d_in, const int* in_sizes, int n_in,
                              void* d_out, int out_size, void* d_ws, size_t ws_size,
                              hipStream_t stream) {
    const float* X        = (const float*)d_in[0];   // [BATCH, IN_DIM]
    const float* W        = (const float*)d_in[1];   // [IN_DIM, D_MODEL]
    const float* Xi       = (const float*)d_in[2];   // [D_MODEL, N_NODES]
    const int*   children = (const int*)d_in[3];     // [N_NODES+1, BRANCH]
    int* out = (int*)d_out;                          // [BATCH, HEIGHT+1] int32

    float* f = (float*)d_ws;                         // [BATCH, D_MODEL] scratch

    dim3 ggrid(BATCH / BM, D_MODEL / BN);
    gemm_f32<<<ggrid, 256, 0, stream>>>(X, W, f);

    descend<<<BATCH / 2, 256, 0, stream>>>(f, Xi, children, out);
}